// Round 1
// 767.131 us; speedup vs baseline: 1.1845x; 1.1845x over previous
//
#include <hip/hip_runtime.h>
#include <cstdint>
#include <cstddef>

#define NFRAMES 8192
#define MDIM    1024
#define Q_SCALE 0.06f

// 8-phase-style GEMM geometry: 256x128 tile, BK=64, 8 waves (4m x 2n, 64x64 each)
#define BM 256
#define BN 128
#define BK 64

typedef __bf16 bf16x8 __attribute__((ext_vector_type(8)));
typedef float  f32x4  __attribute__((ext_vector_type(4)));
typedef unsigned short us8 __attribute__((ext_vector_type(8)));

// fp32 -> bf16 round-to-nearest-even on raw bits
__device__ __forceinline__ unsigned short f2bf(float f) {
  union { float f; uint32_t u; } a; a.f = f;
  uint32_t u = a.u;
  u += 0x7FFFu + ((u >> 16) & 1u);
  return (unsigned short)(u >> 16);
}
__device__ __forceinline__ float bf2f(unsigned short h) {
  union { uint32_t u; float f; } a; a.u = ((uint32_t)h) << 16; return a.f;
}

// async global->LDS, 16B per lane; LDS dest is wave-uniform base (HW adds lane*16)
__device__ __forceinline__ void async_ld16(const void* g, void* l) {
  __builtin_amdgcn_global_load_lds(
      (const __attribute__((address_space(1))) void*)(uintptr_t)g,
      (__attribute__((address_space(3))) void*)(uint32_t)(uintptr_t)l,
      16, 0, 0);
}

__device__ __forceinline__ void store_val(float* p, float v) { *p = v; }
__device__ __forceinline__ void store_val(unsigned short* p, float v) { *p = f2bf(v); }

// C = A * B^T: C[m0+..][n0+..] = sum_k A[row,k]*B[col,k], K multiple of 64.
// 3-deep LDS ring: compute tile t from buf[t%3] while staging tile t+2 into
// buf[(t+2)%3] (never read/written concurrently). One counted vmcnt(6) per
// K-tile (never 0 in steady state), raw s_barriers only (no __syncthreads ->
// no vmcnt(0) drain), setprio around MFMA clusters.
// LDS swizzle: logical (row, byte c) stored at row*128 + (c ^ ((row&7)<<4)).
// global_load_lds writes linearly, so the SOURCE address is inverse-swizzled
// per-lane (slot = (lane&7)^(lane>>3)) and ds_reads apply the same XOR.
template <typename OutT>
__global__ __launch_bounds__(512, 2) void gemm_bt8(
    const unsigned short* __restrict__ A, int lda,
    const unsigned short* __restrict__ B, int ldb,
    OutT* __restrict__ C, int ldc, int K)
{
  __shared__ alignas(16) unsigned short As[3 * BM * BK]; // 96 KB
  __shared__ alignas(16) unsigned short Bs[3 * BN * BK]; // 48 KB

  const int tid  = threadIdx.x;
  const int wave = tid >> 6;
  const int lane = tid & 63;

  // bijective XCD-chunked block swizzle (all call sites have nwg % 8 == 0)
  const int gX  = (int)gridDim.x;
  const int nwg = gX * (int)gridDim.y;
  const int L   = (int)blockIdx.y * gX + (int)blockIdx.x;
  const int qq  = nwg >> 3;
  const int Ls  = (L & 7) * qq + (L >> 3);
  const int bx  = Ls % gX, by = Ls / gX;

  const int m0 = by * BM, n0 = bx * BN;
  const int wm = (wave >> 1) * 64;   // 4 m-waves of 64 rows
  const int wn = (wave & 1) * 64;    // 2 n-waves of 64 cols
  const int fr = lane & 15, fq = lane >> 4;

  // ---- staging addresses: per wave 4 A-instrs + 2 B-instrs per K-tile ----
  // instr (wave, s) covers rows [s*64 + wave*8, +8); lane l -> row +(l>>3),
  // 16B slot (l&7); source slot pre-swizzled by ^(l>>3).
  const int l8 = lane >> 3, l7 = lane & 7;
  const size_t ldaB = (size_t)lda * 2, ldbB = (size_t)ldb * 2;
  const char* aSrc = (const char*)A + (size_t)(m0 + wave * 8 + l8) * ldaB + ((l7 ^ l8) << 4);
  const char* bSrc = (const char*)B + (size_t)(n0 + wave * 8 + l8) * ldbB + ((l7 ^ l8) << 4);
  unsigned short* aDst = As + wave * 512;  // (wave*8 rows) * 64 elems
  unsigned short* bDst = Bs + wave * 512;

  // ---- swizzled ds_read column offsets (bytes); row&7 == fr&7 here ----
  const int xorv = (fr & 7) << 4;
  const int cA0 = (fq * 16) ^ xorv;        // kk=0
  const int cA1 = (64 + fq * 16) ^ xorv;   // kk=1
  const char* aRd = (const char*)As + (wm + fr) * 128;
  const char* bRd = (const char*)Bs + (wn + fr) * 128;

  f32x4 acc[4][4] = {};
  const int NT = K >> 6;

#define STA(buf, s, t) async_ld16(aSrc + (size_t)((s) * 64) * ldaB + (size_t)(t) * 128, \
                                  aDst + (buf) * 16384 + (s) * 4096)
#define STB(buf, s, t) async_ld16(bSrc + (size_t)((s) * 64) * ldbB + (size_t)(t) * 128, \
                                  bDst + (buf) * 8192 + (s) * 4096)

  // prologue: stage tiles 0 and 1 (6 instrs each); wait tile 0 only
  STA(0, 0, 0); STA(0, 1, 0); STA(0, 2, 0); STA(0, 3, 0); STB(0, 0, 0); STB(0, 1, 0);
  if (NT > 1) { STA(1, 0, 1); STA(1, 1, 1); STA(1, 2, 1); STA(1, 3, 1); STB(1, 0, 1); STB(1, 1, 1); }
  asm volatile("s_waitcnt vmcnt(6)" ::: "memory");
  __builtin_amdgcn_s_barrier();

  for (int t = 0; t < NT; ++t) {
    const int cur = t % 3;
    const int u   = t + 2;
    const int ub  = u % 3;
    const bool st = (u < NT);
    const char* aB = aRd + cur * 32768;
    const char* bB = bRd + cur * 16384;

    // ---- phase 0: read B(all 8 frags, held) + A(m0,m1); stage 3; MFMA 16 ----
    bf16x8 bh[4][2];
#pragma unroll
    for (int j = 0; j < 4; ++j) {
      bh[j][0] = *(const bf16x8*)(bB + j * 2048 + cA0);
      bh[j][1] = *(const bf16x8*)(bB + j * 2048 + cA1);
    }
    bf16x8 a0[2][2];
#pragma unroll
    for (int i = 0; i < 2; ++i) {
      a0[i][0] = *(const bf16x8*)(aB + i * 2048 + cA0);
      a0[i][1] = *(const bf16x8*)(aB + i * 2048 + cA1);
    }
    if (st) { STA(ub, 0, u); STA(ub, 1, u); STB(ub, 0, u); }
    __builtin_amdgcn_s_barrier();
    asm volatile("s_waitcnt lgkmcnt(0)" ::: "memory");
    __builtin_amdgcn_sched_barrier(0);
    __builtin_amdgcn_s_setprio(1);
#pragma unroll
    for (int kk = 0; kk < 2; ++kk)
#pragma unroll
      for (int i = 0; i < 2; ++i)
#pragma unroll
        for (int j = 0; j < 4; ++j)
          acc[i][j] = __builtin_amdgcn_mfma_f32_16x16x32_bf16(
              kk ? a0[i][1] : a0[i][0], kk ? bh[j][1] : bh[j][0], acc[i][j], 0, 0, 0);
    __builtin_amdgcn_s_setprio(0);
    __builtin_amdgcn_s_barrier();

    // ---- phase 1: read A(m2,m3); stage 3; tile-boundary counted vmcnt ----
    bf16x8 a1[2][2];
#pragma unroll
    for (int i = 0; i < 2; ++i) {
      a1[i][0] = *(const bf16x8*)(aB + (2 + i) * 2048 + cA0);
      a1[i][1] = *(const bf16x8*)(aB + (2 + i) * 2048 + cA1);
    }
    if (st) { STA(ub, 2, u); STA(ub, 3, u); STB(ub, 1, u); }
    // completes stages(t+1) (issued last tile); leaves stages(t+2) in flight
    if (st) { asm volatile("s_waitcnt vmcnt(6)" ::: "memory"); }
    else    { asm volatile("s_waitcnt vmcnt(0)" ::: "memory"); }
    __builtin_amdgcn_s_barrier();
    asm volatile("s_waitcnt lgkmcnt(0)" ::: "memory");
    __builtin_amdgcn_sched_barrier(0);
    __builtin_amdgcn_s_setprio(1);
#pragma unroll
    for (int kk = 0; kk < 2; ++kk)
#pragma unroll
      for (int i = 0; i < 2; ++i)
#pragma unroll
        for (int j = 0; j < 4; ++j)
          acc[2 + i][j] = __builtin_amdgcn_mfma_f32_16x16x32_bf16(
              kk ? a1[i][1] : a1[i][0], kk ? bh[j][1] : bh[j][0], acc[2 + i][j], 0, 0, 0);
    __builtin_amdgcn_s_setprio(0);
    __builtin_amdgcn_s_barrier();
  }
#undef STA
#undef STB

  // C/D layout (verified m89/m91): col = lane&15, row = (lane>>4)*4 + reg
#pragma unroll
  for (int i = 0; i < 4; ++i)
#pragma unroll
    for (int j = 0; j < 4; ++j)
#pragma unroll
      for (int r = 0; r < 4; ++r) {
        int row = m0 + wm + i * 16 + fq * 4 + r;
        int col = n0 + wn + j * 16 + fr;
        store_val(&C[(size_t)row * ldc + col], acc[i][j][r]);
      }
}

// one block per row: softmax over 8192 cols (bf16 S) + dropout mask, write bf16 P.
__global__ __launch_bounds__(256) void softmax_dropout_kernel(
    const unsigned short* __restrict__ S, const float* __restrict__ U,
    unsigned short* __restrict__ P)
{
  const int row = blockIdx.x;
  const us8*   s8 = (const us8*)(S + (size_t)row * NFRAMES);
  const f32x4* u4 = (const f32x4*)(U + (size_t)row * NFRAMES);
  us8*         p8 = (us8*)(P + (size_t)row * NFRAMES);
  const int tid = threadIdx.x;
  const int lane = tid & 63, wave = tid >> 6;

  float v[32];
  float mx = -3.4e38f;
#pragma unroll
  for (int j = 0; j < 4; ++j) {
    us8 t = __builtin_nontemporal_load(s8 + j * 256 + tid);
#pragma unroll
    for (int e = 0; e < 8; ++e) {
      float f = bf2f(t[e]);
      v[j * 8 + e] = f;
      mx = fmaxf(mx, f);
    }
  }
#pragma unroll
  for (int o = 32; o > 0; o >>= 1) mx = fmaxf(mx, __shfl_xor(mx, o));
  __shared__ float redm[4];
  __shared__ float reds[4];
  if (lane == 0) redm[wave] = mx;
  __syncthreads();
  mx = fmaxf(fmaxf(redm[0], redm[1]), fmaxf(redm[2], redm[3]));

  float sum = 0.f;
#pragma unroll
  for (int i = 0; i < 32; ++i) { v[i] = __expf(v[i] - mx); sum += v[i]; }
#pragma unroll
  for (int o = 32; o > 0; o >>= 1) sum += __shfl_xor(sum, o);
  if (lane == 0) reds[wave] = sum;
  __syncthreads();
  sum = reds[0] + reds[1] + reds[2] + reds[3];
  float inv = 1.0f / sum;

#pragma unroll
  for (int j = 0; j < 4; ++j) {
    f32x4 ua = __builtin_nontemporal_load(u4 + (j * 256 + tid) * 2);
    f32x4 ub = __builtin_nontemporal_load(u4 + (j * 256 + tid) * 2 + 1);
    us8 o;
    o[0] = f2bf(v[j*8+0] * inv * (ua[0] >= 0.5f ? 2.0f : 0.0f));
    o[1] = f2bf(v[j*8+1] * inv * (ua[1] >= 0.5f ? 2.0f : 0.0f));
    o[2] = f2bf(v[j*8+2] * inv * (ua[2] >= 0.5f ? 2.0f : 0.0f));
    o[3] = f2bf(v[j*8+3] * inv * (ua[3] >= 0.5f ? 2.0f : 0.0f));
    o[4] = f2bf(v[j*8+4] * inv * (ub[0] >= 0.5f ? 2.0f : 0.0f));
    o[5] = f2bf(v[j*8+5] * inv * (ub[1] >= 0.5f ? 2.0f : 0.0f));
    o[6] = f2bf(v[j*8+6] * inv * (ub[2] >= 0.5f ? 2.0f : 0.0f));
    o[7] = f2bf(v[j*8+7] * inv * (ub[3] >= 0.5f ? 2.0f : 0.0f));
    p8[j * 256 + tid] = o;
  }
}

__device__ __forceinline__ void cvt4(const float* in, unsigned short* out, int i, float s) {
  float4 t = ((const float4*)in)[i];
  ushort4 o;
  o.x = f2bf(t.x * s); o.y = f2bf(t.y * s); o.z = f2bf(t.z * s); o.w = f2bf(t.w * s);
  ((ushort4*)out)[i] = o;
}

// one launch converts x + all 4 weights; Wq pre-scaled by Q_SCALE; Wk||Wq concatenated
__global__ __launch_bounds__(256) void cvt_all(
    const float* __restrict__ x, const float* __restrict__ Wk,
    const float* __restrict__ Wq, const float* __restrict__ Wv,
    const float* __restrict__ Wo,
    unsigned short* __restrict__ xb, unsigned short* __restrict__ wkq,
    unsigned short* __restrict__ wvb, unsigned short* __restrict__ wob)
{
  int i = blockIdx.x * 256 + threadIdx.x;  // float4 index
  const int XSZ = (NFRAMES * MDIM) / 4;
  const int WSZ = (MDIM * MDIM) / 4;
  if (i < XSZ) { cvt4(x, xb, i, 1.0f); return; }
  i -= XSZ;
  if (i < WSZ) { cvt4(Wk, wkq, i, 1.0f); return; }
  i -= WSZ;
  if (i < WSZ) { cvt4(Wq, wkq + MDIM * MDIM, i, Q_SCALE); return; }
  i -= WSZ;
  if (i < WSZ) { cvt4(Wv, wvb, i, 1.0f); return; }
  i -= WSZ;
  if (i < WSZ) { cvt4(Wo, wob, i, 1.0f); return; }
}

extern "C" void kernel_launch(void* const* d_in, const int* in_sizes, int n_in,
                              void* d_out, int out_size, void* d_ws, size_t ws_size,
                              hipStream_t stream) {
  const float* x  = (const float*)d_in[0];
  const float* Wk = (const float*)d_in[1];
  const float* Wq = (const float*)d_in[2];
  const float* Wv = (const float*)d_in[3];
  const float* Wo = (const float*)d_in[4];
  const float* u  = (const float*)d_in[5];
  float* out = (float*)d_out;

  const int N = NFRAMES, M = MDIM;
  char* base = (char*)d_ws;
  size_t off = 0;
  auto alloc = [&](size_t bytes) -> void* {
    void* p = base + off; off += (bytes + 255) & ~(size_t)255; return p;
  };
  unsigned short* xb  = (unsigned short*)alloc((size_t)N * M * 2);
  unsigned short* wkq = (unsigned short*)alloc((size_t)2 * M * M * 2); // Wk rows then 0.06*Wq rows
  unsigned short* wvb = (unsigned short*)alloc((size_t)M * M * 2);
  unsigned short* wob = (unsigned short*)alloc((size_t)M * M * 2);
  unsigned short* KQb = (unsigned short*)alloc((size_t)N * 2 * M * 2); // [N x 2048]: K | Q
  unsigned short* Vt  = (unsigned short*)alloc((size_t)M * N * 2);     // [M x N] = V^T
  unsigned short* yb  = (unsigned short*)alloc((size_t)N * M * 2);

  // stripe size R (rows of S/P live at once); min 256 (= BM)
  size_t avail = ws_size > off ? ws_size - off : 0;
  int R = 256;
  const int cands[6] = {8192, 4096, 2048, 1024, 512, 256};
  for (int ci = 0; ci < 6; ++ci) {
    size_t need = (size_t)cands[ci] * N * 2 * 2 + 1024;
    if (need <= avail) { R = cands[ci]; break; }
  }
  unsigned short* Sb = (unsigned short*)alloc((size_t)R * N * 2);
  unsigned short* Pb = (unsigned short*)alloc((size_t)R * N * 2);

  // 1. convert inputs to bf16 (one launch)
  {
    int total4 = (N * M + 4 * M * M) / 4;
    cvt_all<<<(total4 + 255) / 256, 256, 0, stream>>>(x, Wk, Wq, Wv, Wo, xb, wkq, wvb, wob);
  }

  // 2. projections: [K|Q] = x @ [Wk|0.06Wq]^T (one GEMM); V^T = Wv x^T
  gemm_bt8<unsigned short><<<dim3(2 * M / BN, N / BM), 512, 0, stream>>>(
      xb, M, wkq, M, KQb, 2 * M, M);
  gemm_bt8<unsigned short><<<dim3(N / BN, M / BM), 512, 0, stream>>>(
      wvb, M, xb, M, Vt, N, M);

  // 3. attention stripes: S = Q K^T (bf16) -> softmax+dropout -> y = P V (full-K, no split)
  for (int i0 = 0; i0 < N; i0 += R) {
    gemm_bt8<unsigned short><<<dim3(N / BN, R / BM), 512, 0, stream>>>(
        KQb + M + (size_t)i0 * 2 * M, 2 * M,   // Q rows i0.., stride 2048
        KQb, 2 * M,                            // K rows, stride 2048
        Sb, N, M);
    softmax_dropout_kernel<<<R, 256, 0, stream>>>(Sb, u + (size_t)i0 * N, Pb);
    gemm_bt8<unsigned short><<<dim3(M / BN, R / BM), 512, 0, stream>>>(
        Pb, N, Vt, N, yb + (size_t)i0 * M, M, N);
  }

  // 4. out = y Wo^T (fp32 straight to d_out)
  gemm_bt8<float><<<dim3(M / BN, N / BM), 512, 0, stream>>>(
      yb, M, wob, M, out, M, M);
}

// Round 2
// 716.806 us; speedup vs baseline: 1.2677x; 1.0702x over previous
//
#include <hip/hip_runtime.h>
#include <cstdint>
#include <cstddef>

#define NFRAMES 8192
#define MDIM    1024
#define Q_SCALE 0.06f

#define BK 64
// big kernel: 256x256 tile, 8 waves (2M x 4N), 128x64 per wave
#define BM2 256
#define BN2 256
// small kernel (round-1, verified): 256x128 tile, 8 waves (4M x 2N), 64x64 per wave
#define BM 256
#define BN 128

typedef __bf16 bf16x8 __attribute__((ext_vector_type(8)));
typedef float  f32x4  __attribute__((ext_vector_type(4)));
typedef unsigned short us8 __attribute__((ext_vector_type(8)));

__device__ __forceinline__ unsigned short f2bf(float f) {
  union { float f; uint32_t u; } a; a.f = f;
  uint32_t u = a.u;
  u += 0x7FFFu + ((u >> 16) & 1u);
  return (unsigned short)(u >> 16);
}
__device__ __forceinline__ float bf2f(unsigned short h) {
  union { uint32_t u; float f; } a; a.u = ((uint32_t)h) << 16; return a.f;
}

__device__ __forceinline__ void async_ld16(const void* g, void* l) {
  __builtin_amdgcn_global_load_lds(
      (const __attribute__((address_space(1))) void*)(uintptr_t)g,
      (__attribute__((address_space(3))) void*)(uint32_t)(uintptr_t)l,
      16, 0, 0);
}

__device__ __forceinline__ void store_val(float* p, float v) { *p = v; }
__device__ __forceinline__ void store_val(unsigned short* p, float v) { *p = f2bf(v); }

// ---------------------------------------------------------------------------
// BIG: C = A * B^T, 256x256 tile, 8 waves of 128x64, BK=64, ping-pong LDS.
// Per K-tile: stage all 8 loads of tile t+1 at top (full tile of compute to
// land), NO intra-tile barriers (waves slip -> ds_read/MFMA overlap across
// the 2 waves/SIMD), one vmcnt(0)+s_barrier at the tile boundary.
// LDS swizzle identical to verified round-1: byte c of row r stored at
// c ^ ((r&7)<<4); global_load_lds dest linear, source slot pre-swizzled.
// Optional split-K via blockIdx.z: kOff = z*kChunk, partial at C + z*cz.
// ---------------------------------------------------------------------------
template <typename OutT>
__global__ __launch_bounds__(512, 2) void gemm_big(
    const unsigned short* __restrict__ A, int lda,
    const unsigned short* __restrict__ B, int ldb,
    OutT* __restrict__ C, int ldc, long cz, int kChunk)
{
  __shared__ alignas(16) unsigned short As[2 * BM2 * BK]; // 64 KB
  __shared__ alignas(16) unsigned short Bs[2 * BN2 * BK]; // 64 KB

  const int tid  = threadIdx.x;
  const int wave = tid >> 6;
  const int lane = tid & 63;

  // bijective XCD-chunked swizzle (identity if nwg % 8 != 0)
  const int gX  = (int)gridDim.x;
  const int nwg = gX * (int)gridDim.y;
  int bx = (int)blockIdx.x, by = (int)blockIdx.y;
  if ((nwg & 7) == 0) {
    const int L  = by * gX + bx;
    const int qq = nwg >> 3;
    const int Ls = (L & 7) * qq + (L >> 3);
    bx = Ls % gX; by = Ls / gX;
  }

  const int m0 = by * BM2, n0 = bx * BN2;
  const int wm = (wave >> 2) * 128;  // 2 M-groups of 128 rows
  const int wn = (wave & 3) * 64;    // 4 N-groups of 64 cols
  const int fr = lane & 15, fq = lane >> 4;

  const int kOff = (int)blockIdx.z * kChunk;
  OutT* Cz = C + (size_t)blockIdx.z * cz;

  // staging: instr s covers rows [s*64, s*64+64); lane -> row +(l>>3),
  // 16B slot (l&7), source slot pre-swizzled ^(l>>3)  [w*8 == 0 mod 8]
  const int l8 = lane >> 3, l7 = lane & 7;
  const size_t ldaB = (size_t)lda * 2, ldbB = (size_t)ldb * 2;
  const char* aSrc = (const char*)A + (size_t)(m0 + wave * 8 + l8) * ldaB
                     + (size_t)kOff * 2 + ((l7 ^ l8) << 4);
  const char* bSrc = (const char*)B + (size_t)(n0 + wave * 8 + l8) * ldbB
                     + (size_t)kOff * 2 + ((l7 ^ l8) << 4);
  unsigned short* aDst = As + wave * 512;
  unsigned short* bDst = Bs + wave * 512;

  const int xorv = (fr & 7) << 4;
  const int c0 = (fq * 16) ^ xorv;         // kk=0 byte col (swizzled)
  const int c1 = (64 + fq * 16) ^ xorv;    // kk=1
  const char* aRd = (const char*)As + (wm + fr) * 128;
  const char* bRd = (const char*)Bs + (wn + fr) * 128;

  f32x4 acc[8][4] = {};
  const int NT = kChunk >> 6;

#define STA2(buf, s, t) async_ld16(aSrc + (size_t)((s) * 64) * ldaB + (size_t)(t) * 128, \
                                   aDst + (buf) * 16384 + (s) * 4096)
#define STB2(buf, s, t) async_ld16(bSrc + (size_t)((s) * 64) * ldbB + (size_t)(t) * 128, \
                                   bDst + (buf) * 16384 + (s) * 4096)

  // prologue: stage tile 0 into buf 0, drain, barrier
  STA2(0, 0, 0); STA2(0, 1, 0); STA2(0, 2, 0); STA2(0, 3, 0);
  STB2(0, 0, 0); STB2(0, 1, 0); STB2(0, 2, 0); STB2(0, 3, 0);
  asm volatile("s_waitcnt vmcnt(0)" ::: "memory");
  __builtin_amdgcn_s_barrier();

  for (int t = 0; t < NT; ++t) {
    const int cur = t & 1;
    const bool st = (t + 1 < NT);
    const char* aB = aRd + cur * 32768;
    const char* bB = bRd + cur * 32768;

    // issue next tile's stages FIRST (they have the whole tile to land)
    if (st) {
      const int u = t + 1, ub = cur ^ 1;
      STA2(ub, 0, u); STA2(ub, 1, u); STA2(ub, 2, u); STA2(ub, 3, u);
      STB2(ub, 0, u); STB2(ub, 1, u); STB2(ub, 2, u); STB2(ub, 3, u);
    }
    __builtin_amdgcn_sched_barrier(0);  // keep stages ahead of ds_reads

    // B frags (held for whole tile) + first A pair
    bf16x8 bh[4][2];
#pragma unroll
    for (int j = 0; j < 4; ++j) {
      bh[j][0] = *(const bf16x8*)(bB + j * 2048 + c0);
      bh[j][1] = *(const bf16x8*)(bB + j * 2048 + c1);
    }
    bf16x8 ar[2][2][2];
#pragma unroll
    for (int i = 0; i < 2; ++i) {
      ar[0][i][0] = *(const bf16x8*)(aB + i * 2048 + c0);
      ar[0][i][1] = *(const bf16x8*)(aB + i * 2048 + c1);
    }

    // 4 phases: MFMA phase p while reading A-frags of phase p+1
#pragma unroll
    for (int ph = 0; ph < 4; ++ph) {
      const int pc = ph & 1, pn = pc ^ 1;
      if (ph < 3) {
#pragma unroll
        for (int i = 0; i < 2; ++i) {
          ar[pn][i][0] = *(const bf16x8*)(aB + (ph * 2 + 2 + i) * 2048 + c0);
          ar[pn][i][1] = *(const bf16x8*)(aB + (ph * 2 + 2 + i) * 2048 + c1);
        }
      }
      __builtin_amdgcn_s_setprio(1);
#pragma unroll
      for (int kk = 0; kk < 2; ++kk)
#pragma unroll
        for (int i = 0; i < 2; ++i)
#pragma unroll
          for (int j = 0; j < 4; ++j)
            acc[ph * 2 + i][j] = __builtin_amdgcn_mfma_f32_16x16x32_bf16(
                ar[pc][i][kk], bh[j][kk], acc[ph * 2 + i][j], 0, 0, 0);
      __builtin_amdgcn_s_setprio(0);
    }

    if (st) { asm volatile("s_waitcnt vmcnt(0)" ::: "memory"); }
    __builtin_amdgcn_s_barrier();
  }
#undef STA2
#undef STB2

  // C/D layout (verified m89/m91): col = lane&15, row = (lane>>4)*4 + reg
#pragma unroll
  for (int mf = 0; mf < 8; ++mf)
#pragma unroll
    for (int nf = 0; nf < 4; ++nf)
#pragma unroll
      for (int r = 0; r < 4; ++r) {
        int row = m0 + wm + mf * 16 + fq * 4 + r;
        int col = n0 + wn + nf * 16 + fr;
        store_val(&Cz[(size_t)row * ldc + col], acc[mf][nf][r]);
      }
}

// ---------------------------------------------------------------------------
// SMALL (round-1, verified): 256x128 tile, 8 waves of 64x64, 3-deep ring.
// Used where the 256-wide tile would leave the grid under 256 blocks.
// ---------------------------------------------------------------------------
template <typename OutT>
__global__ __launch_bounds__(512, 2) void gemm_bt8(
    const unsigned short* __restrict__ A, int lda,
    const unsigned short* __restrict__ B, int ldb,
    OutT* __restrict__ C, int ldc, int K)
{
  __shared__ alignas(16) unsigned short As[3 * BM * BK]; // 96 KB
  __shared__ alignas(16) unsigned short Bs[3 * BN * BK]; // 48 KB

  const int tid  = threadIdx.x;
  const int wave = tid >> 6;
  const int lane = tid & 63;

  const int gX  = (int)gridDim.x;
  const int nwg = gX * (int)gridDim.y;
  const int L   = (int)blockIdx.y * gX + (int)blockIdx.x;
  const int qq  = nwg >> 3;
  const int Ls  = (L & 7) * qq + (L >> 3);
  const int bx  = Ls % gX, by = Ls / gX;

  const int m0 = by * BM, n0 = bx * BN;
  const int wm = (wave >> 1) * 64;
  const int wn = (wave & 1) * 64;
  const int fr = lane & 15, fq = lane >> 4;

  const int l8 = lane >> 3, l7 = lane & 7;
  const size_t ldaB = (size_t)lda * 2, ldbB = (size_t)ldb * 2;
  const char* aSrc = (const char*)A + (size_t)(m0 + wave * 8 + l8) * ldaB + ((l7 ^ l8) << 4);
  const char* bSrc = (const char*)B + (size_t)(n0 + wave * 8 + l8) * ldbB + ((l7 ^ l8) << 4);
  unsigned short* aDst = As + wave * 512;
  unsigned short* bDst = Bs + wave * 512;

  const int xorv = (fr & 7) << 4;
  const int cA0 = (fq * 16) ^ xorv;
  const int cA1 = (64 + fq * 16) ^ xorv;
  const char* aRd = (const char*)As + (wm + fr) * 128;
  const char* bRd = (const char*)Bs + (wn + fr) * 128;

  f32x4 acc[4][4] = {};
  const int NT = K >> 6;

#define STA(buf, s, t) async_ld16(aSrc + (size_t)((s) * 64) * ldaB + (size_t)(t) * 128, \
                                  aDst + (buf) * 16384 + (s) * 4096)
#define STB(buf, s, t) async_ld16(bSrc + (size_t)((s) * 64) * ldbB + (size_t)(t) * 128, \
                                  bDst + (buf) * 8192 + (s) * 4096)

  STA(0, 0, 0); STA(0, 1, 0); STA(0, 2, 0); STA(0, 3, 0); STB(0, 0, 0); STB(0, 1, 0);
  if (NT > 1) { STA(1, 0, 1); STA(1, 1, 1); STA(1, 2, 1); STA(1, 3, 1); STB(1, 0, 1); STB(1, 1, 1); }
  asm volatile("s_waitcnt vmcnt(6)" ::: "memory");
  __builtin_amdgcn_s_barrier();

  for (int t = 0; t < NT; ++t) {
    const int cur = t % 3;
    const int u   = t + 2;
    const int ub  = u % 3;
    const bool st = (u < NT);
    const char* aB = aRd + cur * 32768;
    const char* bB = bRd + cur * 16384;

    bf16x8 bh[4][2];
#pragma unroll
    for (int j = 0; j < 4; ++j) {
      bh[j][0] = *(const bf16x8*)(bB + j * 2048 + cA0);
      bh[j][1] = *(const bf16x8*)(bB + j * 2048 + cA1);
    }
    bf16x8 a0[2][2];
#pragma unroll
    for (int i = 0; i < 2; ++i) {
      a0[i][0] = *(const bf16x8*)(aB + i * 2048 + cA0);
      a0[i][1] = *(const bf16x8*)(aB + i * 2048 + cA1);
    }
    if (st) { STA(ub, 0, u); STA(ub, 1, u); STB(ub, 0, u); }
    __builtin_amdgcn_s_barrier();
    asm volatile("s_waitcnt lgkmcnt(0)" ::: "memory");
    __builtin_amdgcn_sched_barrier(0);
    __builtin_amdgcn_s_setprio(1);
#pragma unroll
    for (int kk = 0; kk < 2; ++kk)
#pragma unroll
      for (int i = 0; i < 2; ++i)
#pragma unroll
        for (int j = 0; j < 4; ++j)
          acc[i][j] = __builtin_amdgcn_mfma_f32_16x16x32_bf16(
              kk ? a0[i][1] : a0[i][0], kk ? bh[j][1] : bh[j][0], acc[i][j], 0, 0, 0);
    __builtin_amdgcn_s_setprio(0);
    __builtin_amdgcn_s_barrier();

    bf16x8 a1[2][2];
#pragma unroll
    for (int i = 0; i < 2; ++i) {
      a1[i][0] = *(const bf16x8*)(aB + (2 + i) * 2048 + cA0);
      a1[i][1] = *(const bf16x8*)(aB + (2 + i) * 2048 + cA1);
    }
    if (st) { STA(ub, 2, u); STA(ub, 3, u); STB(ub, 1, u); }
    if (st) { asm volatile("s_waitcnt vmcnt(6)" ::: "memory"); }
    else    { asm volatile("s_waitcnt vmcnt(0)" ::: "memory"); }
    __builtin_amdgcn_s_barrier();
    asm volatile("s_waitcnt lgkmcnt(0)" ::: "memory");
    __builtin_amdgcn_sched_barrier(0);
    __builtin_amdgcn_s_setprio(1);
#pragma unroll
    for (int kk = 0; kk < 2; ++kk)
#pragma unroll
      for (int i = 0; i < 2; ++i)
#pragma unroll
        for (int j = 0; j < 4; ++j)
          acc[2 + i][j] = __builtin_amdgcn_mfma_f32_16x16x32_bf16(
              kk ? a1[i][1] : a1[i][0], kk ? bh[j][1] : bh[j][0], acc[2 + i][j], 0, 0, 0);
    __builtin_amdgcn_s_setprio(0);
    __builtin_amdgcn_s_barrier();
  }
#undef STA
#undef STB

#pragma unroll
  for (int i = 0; i < 4; ++i)
#pragma unroll
    for (int j = 0; j < 4; ++j)
#pragma unroll
      for (int r = 0; r < 4; ++r) {
        int row = m0 + wm + i * 16 + fq * 4 + r;
        int col = n0 + wn + j * 16 + fr;
        store_val(&C[(size_t)row * ldc + col], acc[i][j][r]);
      }
}

// one block per row: softmax over 8192 cols (bf16 S) + dropout mask, write bf16 P.
__global__ __launch_bounds__(256) void softmax_dropout_kernel(
    const unsigned short* __restrict__ S, const float* __restrict__ U,
    unsigned short* __restrict__ P)
{
  const int row = blockIdx.x;
  const us8*   s8 = (const us8*)(S + (size_t)row * NFRAMES);
  const f32x4* u4 = (const f32x4*)(U + (size_t)row * NFRAMES);
  us8*         p8 = (us8*)(P + (size_t)row * NFRAMES);
  const int tid = threadIdx.x;
  const int lane = tid & 63, wave = tid >> 6;

  float v[32];
  float mx = -3.4e38f;
#pragma unroll
  for (int j = 0; j < 4; ++j) {
    us8 t = __builtin_nontemporal_load(s8 + j * 256 + tid);
#pragma unroll
    for (int e = 0; e < 8; ++e) {
      float f = bf2f(t[e]);
      v[j * 8 + e] = f;
      mx = fmaxf(mx, f);
    }
  }
#pragma unroll
  for (int o = 32; o > 0; o >>= 1) mx = fmaxf(mx, __shfl_xor(mx, o));
  __shared__ float redm[4];
  __shared__ float reds[4];
  if (lane == 0) redm[wave] = mx;
  __syncthreads();
  mx = fmaxf(fmaxf(redm[0], redm[1]), fmaxf(redm[2], redm[3]));

  float sum = 0.f;
#pragma unroll
  for (int i = 0; i < 32; ++i) { v[i] = __expf(v[i] - mx); sum += v[i]; }
#pragma unroll
  for (int o = 32; o > 0; o >>= 1) sum += __shfl_xor(sum, o);
  if (lane == 0) reds[wave] = sum;
  __syncthreads();
  sum = reds[0] + reds[1] + reds[2] + reds[3];
  float inv = 1.0f / sum;

#pragma unroll
  for (int j = 0; j < 4; ++j) {
    f32x4 ua = __builtin_nontemporal_load(u4 + (j * 256 + tid) * 2);
    f32x4 ub = __builtin_nontemporal_load(u4 + (j * 256 + tid) * 2 + 1);
    us8 o;
    o[0] = f2bf(v[j*8+0] * inv * (ua[0] >= 0.5f ? 2.0f : 0.0f));
    o[1] = f2bf(v[j*8+1] * inv * (ua[1] >= 0.5f ? 2.0f : 0.0f));
    o[2] = f2bf(v[j*8+2] * inv * (ua[2] >= 0.5f ? 2.0f : 0.0f));
    o[3] = f2bf(v[j*8+3] * inv * (ua[3] >= 0.5f ? 2.0f : 0.0f));
    o[4] = f2bf(v[j*8+4] * inv * (ub[0] >= 0.5f ? 2.0f : 0.0f));
    o[5] = f2bf(v[j*8+5] * inv * (ub[1] >= 0.5f ? 2.0f : 0.0f));
    o[6] = f2bf(v[j*8+6] * inv * (ub[2] >= 0.5f ? 2.0f : 0.0f));
    o[7] = f2bf(v[j*8+7] * inv * (ub[3] >= 0.5f ? 2.0f : 0.0f));
    p8[j * 256 + tid] = o;
  }
}

__device__ __forceinline__ void cvt4(const float* in, unsigned short* out, int i, float s) {
  float4 t = ((const float4*)in)[i];
  ushort4 o;
  o.x = f2bf(t.x * s); o.y = f2bf(t.y * s); o.z = f2bf(t.z * s); o.w = f2bf(t.w * s);
  ((ushort4*)out)[i] = o;
}

__global__ __launch_bounds__(256) void cvt_all(
    const float* __restrict__ x, const float* __restrict__ Wk,
    const float* __restrict__ Wq, const float* __restrict__ Wv,
    const float* __restrict__ Wo,
    unsigned short* __restrict__ xb, unsigned short* __restrict__ wkq,
    unsigned short* __restrict__ wvb, unsigned short* __restrict__ wob)
{
  int i = blockIdx.x * 256 + threadIdx.x;
  const int XSZ = (NFRAMES * MDIM) / 4;
  const int WSZ = (MDIM * MDIM) / 4;
  if (i < XSZ) { cvt4(x, xb, i, 1.0f); return; }
  i -= XSZ;
  if (i < WSZ) { cvt4(Wk, wkq, i, 1.0f); return; }
  i -= WSZ;
  if (i < WSZ) { cvt4(Wq, wkq + MDIM * MDIM, i, Q_SCALE); return; }
  i -= WSZ;
  if (i < WSZ) { cvt4(Wv, wvb, i, 1.0f); return; }
  i -= WSZ;
  if (i < WSZ) { cvt4(Wo, wob, i, 1.0f); return; }
}

// yb = bf16(P0 + P1) for split-K=2 PV partials
__global__ __launch_bounds__(256) void reduce2_bf16(
    const float* __restrict__ Yp, long zs,
    unsigned short* __restrict__ out, int n4)
{
  int i = blockIdx.x * 256 + threadIdx.x;
  if (i < n4) {
    f32x4 a = __builtin_nontemporal_load((const f32x4*)Yp + i);
    f32x4 b = __builtin_nontemporal_load((const f32x4*)(Yp + zs) + i);
    ushort4 o;
    o.x = f2bf(a[0] + b[0]);
    o.y = f2bf(a[1] + b[1]);
    o.z = f2bf(a[2] + b[2]);
    o.w = f2bf(a[3] + b[3]);
    ((ushort4*)out)[i] = o;
  }
}

extern "C" void kernel_launch(void* const* d_in, const int* in_sizes, int n_in,
                              void* d_out, int out_size, void* d_ws, size_t ws_size,
                              hipStream_t stream) {
  const float* x  = (const float*)d_in[0];
  const float* Wk = (const float*)d_in[1];
  const float* Wq = (const float*)d_in[2];
  const float* Wv = (const float*)d_in[3];
  const float* Wo = (const float*)d_in[4];
  const float* u  = (const float*)d_in[5];
  float* out = (float*)d_out;

  const int N = NFRAMES, M = MDIM;
  char* base = (char*)d_ws;
  size_t off = 0;
  auto alloc = [&](size_t bytes) -> void* {
    void* p = base + off; off += (bytes + 255) & ~(size_t)255; return p;
  };
  unsigned short* xb  = (unsigned short*)alloc((size_t)N * M * 2);
  unsigned short* wkq = (unsigned short*)alloc((size_t)2 * M * M * 2);
  unsigned short* wvb = (unsigned short*)alloc((size_t)M * M * 2);
  unsigned short* wob = (unsigned short*)alloc((size_t)M * M * 2);
  unsigned short* KQb = (unsigned short*)alloc((size_t)N * 2 * M * 2); // [N x 2048]: K | Q
  unsigned short* Vt  = (unsigned short*)alloc((size_t)M * N * 2);     // [M x N] = V^T
  unsigned short* yb  = (unsigned short*)alloc((size_t)N * M * 2);

  size_t avail = ws_size > off ? ws_size - off : 0;
  int R = 256;
  const int cands[6] = {8192, 4096, 2048, 1024, 512, 256};
  for (int ci = 0; ci < 6; ++ci) {
    size_t need = (size_t)cands[ci] * N * 2 * 2 + 1024;
    if (need <= avail) { R = cands[ci]; break; }
  }
  unsigned short* Sb = (unsigned short*)alloc((size_t)R * N * 2);
  unsigned short* Pb = (unsigned short*)alloc((size_t)R * N * 2);
  float* Yp = (float*)Sb;  // split-K=2 PV partials (8*R*M B) alias dead S stripe (16*R*N B)

  // 1. convert inputs to bf16
  {
    int total4 = (N * M + 4 * M * M) / 4;
    cvt_all<<<(total4 + 255) / 256, 256, 0, stream>>>(x, Wk, Wq, Wv, Wo, xb, wkq, wvb, wob);
  }

  // 2. projections: [K|Q] = x @ [Wk|0.06Wq]^T (big, 256 blocks); V^T = Wv x^T (small, 256 blocks)
  gemm_big<unsigned short><<<dim3(2 * M / BN2, N / BM2), 512, 0, stream>>>(
      xb, M, wkq, M, KQb, 2 * M, 0, M);
  gemm_bt8<unsigned short><<<dim3(N / BN, M / BM), 512, 0, stream>>>(
      wvb, M, xb, M, Vt, N, M);

  // 3. attention: S = Q K^T (big) -> softmax+dropout -> y = P V (big, split-K=2) -> reduce
  for (int i0 = 0; i0 < N; i0 += R) {
    gemm_big<unsigned short><<<dim3(N / BN2, R / BM2), 512, 0, stream>>>(
        KQb + M + (size_t)i0 * 2 * M, 2 * M,
        KQb, 2 * M,
        Sb, N, 0, M);
    softmax_dropout_kernel<<<R, 256, 0, stream>>>(Sb, u + (size_t)i0 * N, Pb);
    gemm_big<float><<<dim3(M / BN2, R / BM2, 2), 512, 0, stream>>>(
        Pb, N, Vt, N, Yp, M, (long)R * M, N / 2);
    reduce2_bf16<<<(R * M / 4 + 255) / 256, 256, 0, stream>>>(
        Yp, (long)R * M, yb + (size_t)i0 * M, R * M / 4);
  }

  // 4. out = y Wo^T (small, 256 blocks)
  gemm_bt8<float><<<dim3(M / BN, N / BM), 512, 0, stream>>>(
      yb, M, wob, M, out, M, M);
}